// Round 1
// baseline (404.517 us; speedup 1.0000x reference)
//
#include <hip/hip_runtime.h>

#define B_ 4
#define W_ 2048
#define C_ 1024
#define NH 16
#define KH 64

typedef __attribute__((ext_vector_type(8))) short short8;
typedef __attribute__((ext_vector_type(4))) float f32x4;

__device__ __forceinline__ short f2bf(float f) {
    unsigned u = __builtin_bit_cast(unsigned, f);
    u = (u + 0x7FFFu + ((u >> 16) & 1u)) >> 16;
    return (short)u;
}

// ---------------- metric[n] = P[n] @ P[n]^T ----------------
__global__ __launch_bounds__(256) void k_metric(const float* __restrict__ P, float* __restrict__ M) {
    int n = blockIdx.x;
    __shared__ float sP[KH * KH];
    __shared__ float sPt[KH * 65];
    const float* Pn = P + n * KH * KH;
    for (int i = threadIdx.x; i < KH * KH; i += 256) {
        float v = Pn[i];
        sP[i] = v;
        sPt[(i & 63) * 65 + (i >> 6)] = v;  // sPt[j*65+i2] = P[i2][j]
    }
    __syncthreads();
    float* Mn = M + n * KH * KH;
    for (int e = threadIdx.x; e < KH * KH; e += 256) {
        int i = e >> 6, k = e & 63;
        float s = 0.f;
        #pragma unroll 8
        for (int j = 0; j < KH; ++j) s += sP[i * KH + j] * sPt[j * 65 + k];
        Mn[e] = s;  // M[n][i][k]
    }
}

// ---------------- Wq[n*64+jj][c] = sum_k M[n][k][jj] * Wp[n*64+k][c]  (bf16 out) ----------------
__global__ __launch_bounds__(256) void k_wq(const float* __restrict__ M, const float* __restrict__ Wp,
                                            short* __restrict__ Wq) {
    int n = blockIdx.y, cseg = blockIdx.x;
    __shared__ float sM[KH * KH];
    __shared__ float sW[KH * KH];
    for (int i = threadIdx.x; i < KH * KH; i += 256) {
        sM[i] = M[n * KH * KH + i];                       // sM[k*64+jj]
        int r = i >> 6, c = i & 63;
        sW[i] = Wp[(n * KH + r) * C_ + cseg * KH + c];    // sW[k*64+c]
    }
    __syncthreads();
    for (int e = threadIdx.x; e < KH * KH; e += 256) {
        int jj = e >> 6, c = e & 63;
        float s = 0.f;
        #pragma unroll 8
        for (int k = 0; k < KH; ++k) s += sM[k * KH + jj] * sW[k * KH + c];
        Wq[(n * KH + jj) * C_ + cseg * KH + c] = f2bf(s);
    }
}

// ---------------- Wf[o][n*64+k] = sum_j T[n][k][j] * Wm[o][n*64+j]  (bf16 out) ----------------
__global__ __launch_bounds__(256) void k_wf(const float* __restrict__ T, const float* __restrict__ Wm,
                                            short* __restrict__ Wf) {
    int n = blockIdx.y, oseg = blockIdx.x;
    __shared__ float sTt[KH * 65];   // sTt[j*65+k] = T[n][k][j]
    __shared__ float sW[KH * KH];    // sW[r*64+j] = Wm[oseg*64+r][n*64+j]
    for (int i = threadIdx.x; i < KH * KH; i += 256) {
        sTt[(i & 63) * 65 + (i >> 6)] = T[n * KH * KH + i];
        int r = i >> 6, c = i & 63;
        sW[i] = Wm[(oseg * KH + r) * C_ + n * KH + c];
    }
    __syncthreads();
    for (int e = threadIdx.x; e < KH * KH; e += 256) {
        int r = e >> 6, k = e & 63;
        float s = 0.f;
        #pragma unroll 8
        for (int j = 0; j < KH; ++j) s += sTt[j * 65 + k] * sW[r * KH + j];
        Wf[(oseg * KH + r) * C_ + n * KH + k] = f2bf(s);
    }
}

// ---------------- fp32 -> bf16 convert ----------------
__global__ __launch_bounds__(256) void k_cvt(const float* __restrict__ src, short* __restrict__ dst, int n4) {
    int i = blockIdx.x * 256 + threadIdx.x;
    if (i < n4) {
        float4 v = ((const float4*)src)[i];
        short4 o;
        o.x = f2bf(v.x); o.y = f2bf(v.y); o.z = f2bf(v.z); o.w = f2bf(v.w);
        ((short4*)dst)[i] = o;
    }
}

// ---------------- Out[M][1024] = A[M][1024] @ Bw[1024][1024]^T  (bf16 MFMA, 128x128 tile) ----------------
template <bool OUT_FP32>
__global__ __launch_bounds__(256) void k_gemm(const short* __restrict__ A, const short* __restrict__ Bw,
                                              void* __restrict__ Out) {
    __shared__ short As[128 * 72];
    __shared__ short Bs[128 * 72];
    int bm = blockIdx.y, bn = blockIdx.x;
    int t = threadIdx.x;
    int wave = t >> 6, lane = t & 63;
    int q = lane >> 4, c = lane & 15;
    int wy = wave >> 1, wx = wave & 1;
    f32x4 acc[4][4] = {};
    for (int k0 = 0; k0 < C_; k0 += 64) {
        __syncthreads();
        #pragma unroll
        for (int e = 0; e < 4; ++e) {
            int ch = e * 256 + t;           // 1024 chunks of 8 bf16
            int row = ch >> 3, sub = ch & 7;
            *(short8*)&As[row * 72 + sub * 8] = *(const short8*)&A[(bm * 128 + row) * C_ + k0 + sub * 8];
            *(short8*)&Bs[row * 72 + sub * 8] = *(const short8*)&Bw[(bn * 128 + row) * C_ + k0 + sub * 8];
        }
        __syncthreads();
        #pragma unroll
        for (int kk = 0; kk < 64; kk += 32) {
            short8 af[4], bfr[4];
            #pragma unroll
            for (int i = 0; i < 4; ++i)
                af[i] = *(const short8*)&As[(wy * 64 + i * 16 + c) * 72 + kk + q * 8];
            #pragma unroll
            for (int j = 0; j < 4; ++j)
                bfr[j] = *(const short8*)&Bs[(wx * 64 + j * 16 + c) * 72 + kk + q * 8];
            #pragma unroll
            for (int i = 0; i < 4; ++i)
                #pragma unroll
                for (int j = 0; j < 4; ++j)
                    acc[i][j] = __builtin_amdgcn_mfma_f32_16x16x32_bf16(af[i], bfr[j], acc[i][j], 0, 0, 0);
        }
    }
    #pragma unroll
    for (int i = 0; i < 4; ++i)
        #pragma unroll
        for (int j = 0; j < 4; ++j)
            #pragma unroll
            for (int r = 0; r < 4; ++r) {
                int row = bm * 128 + wy * 64 + i * 16 + q * 4 + r;
                int col = bn * 128 + wx * 64 + j * 16 + c;
                if (OUT_FP32) ((float*)Out)[row * C_ + col] = acc[i][j][r];
                else ((short*)Out)[row * C_ + col] = f2bf(acc[i][j][r]);
            }
}

// ---------------- fused causal scores->nudged (flash-style) ----------------
// grid (32 w-tiles, 16 heads, 4 batch), 256 thr. Each wave owns a 16-row strip of the 64-row tile.
__global__ __launch_bounds__(256) void k_flash(const short* __restrict__ Qm, const short* __restrict__ Pj,
                                               short* __restrict__ Nd) {
    int wt = blockIdx.x, n = blockIdx.y, b = blockIdx.z;
    int t = threadIdx.x, wave = t >> 6, lane = t & 63;
    int q = lane >> 4, c = lane & 15;
    __shared__ short Ps[64 * 72];       // P v-tile, row-major [v][k]
    __shared__ short Ss[4][16 * 72];    // per-wave S strip, [w][v]
    int w0 = wt * 64;
    int myrow = w0 + wave * 16 + c;
    short8 aq[2];
    #pragma unroll
    for (int ch = 0; ch < 2; ++ch)
        aq[ch] = *(const short8*)&Qm[(b * W_ + myrow) * C_ + n * KH + ch * 32 + q * 8];
    f32x4 oc[4] = {};
    for (int vt = 0; vt <= wt; ++vt) {
        __syncthreads();
        #pragma unroll
        for (int e = 0; e < 2; ++e) {
            int ch = e * 256 + t;       // 512 chunks of 8 bf16
            int row = ch >> 3, sub = ch & 7;
            *(short8*)&Ps[row * 72 + sub * 8] =
                *(const short8*)&Pj[(b * W_ + vt * 64 + row) * C_ + n * KH + sub * 8];
        }
        __syncthreads();
        // S = qm @ P^T / 8, masked on diagonal tile; store strip to LDS as A-layout
        #pragma unroll
        for (int ct = 0; ct < 4; ++ct) {
            f32x4 s = {};
            #pragma unroll
            for (int ch = 0; ch < 2; ++ch) {
                short8 pb = *(const short8*)&Ps[(ct * 16 + c) * 72 + ch * 32 + q * 8];
                s = __builtin_amdgcn_mfma_f32_16x16x32_bf16(aq[ch], pb, s, 0, 0, 0);
            }
            #pragma unroll
            for (int r = 0; r < 4; ++r) {
                float v = s[r] * 0.125f;
                if (vt == wt) {
                    int vcol = vt * 64 + ct * 16 + c;
                    int wrow = w0 + wave * 16 + q * 4 + r;
                    if (vcol > wrow) v = 0.f;
                }
                Ss[wave][(q * 4 + r) * 72 + ct * 16 + c] = f2bf(v);
            }
        }
        // O += S @ P   (B-frags of P read column-strided)
        #pragma unroll
        for (int ch = 0; ch < 2; ++ch) {
            short8 as_ = *(const short8*)&Ss[wave][c * 72 + ch * 32 + q * 8];
            #pragma unroll
            for (int ct2 = 0; ct2 < 4; ++ct2) {
                short8 pb;
                #pragma unroll
                for (int j = 0; j < 8; ++j)
                    pb[j] = Ps[(ch * 32 + q * 8 + j) * 72 + ct2 * 16 + c];
                oc[ct2] = __builtin_amdgcn_mfma_f32_16x16x32_bf16(as_, pb, oc[ct2], 0, 0, 0);
            }
        }
    }
    #pragma unroll
    for (int ct2 = 0; ct2 < 4; ++ct2)
        #pragma unroll
        for (int r = 0; r < 4; ++r) {
            int wrow = w0 + wave * 16 + q * 4 + r;
            Nd[(b * W_ + wrow) * C_ + n * KH + ct2 * 16 + c] = f2bf(oc[ct2][r]);
        }
}

extern "C" void kernel_launch(void* const* d_in, const int* in_sizes, int n_in,
                              void* d_out, int out_size, void* d_ws, size_t ws_size,
                              hipStream_t stream) {
    const float* x  = (const float*)d_in[0];
    const float* Wp = (const float*)d_in[1];
    const float* Pm = (const float*)d_in[2];
    const float* Tr = (const float*)d_in[3];
    const float* Wm = (const float*)d_in[4];
    float* out = (float*)d_out;
    char* ws = (char*)d_ws;

    float* metric = (float*)ws;                                   // 256 KB
    short* wq16 = (short*)(ws + 0x40000);                         // 2 MB
    short* wf16 = (short*)(ws + 0x40000 + 0x200000);              // 2 MB
    short* wp16 = (short*)(ws + 0x40000 + 2 * 0x200000);          // 2 MB
    short* x16  = (short*)(ws + 0x40000 + 3 * 0x200000);          // 16 MB
    short* pj16 = x16 + 8 * 1024 * 1024;                          // 16 MB
    short* qm16 = pj16 + 8 * 1024 * 1024;                         // 16 MB
    short* nd16 = x16;                                            // alias: x16 dead after GEMMs

    k_metric<<<dim3(NH), dim3(256), 0, stream>>>(Pm, metric);
    k_wq<<<dim3(16, NH), dim3(256), 0, stream>>>(metric, Wp, wq16);
    k_wf<<<dim3(16, NH), dim3(256), 0, stream>>>(Tr, Wm, wf16);
    k_cvt<<<dim3(8192), dim3(256), 0, stream>>>(x, x16, (B_ * W_ * C_) / 4);
    k_cvt<<<dim3(1024), dim3(256), 0, stream>>>(Wp, wp16, (C_ * C_) / 4);

    k_gemm<false><<<dim3(8, 64), dim3(256), 0, stream>>>(x16, wp16, (void*)pj16);
    k_gemm<false><<<dim3(8, 64), dim3(256), 0, stream>>>(x16, wq16, (void*)qm16);
    k_flash<<<dim3(32, NH, B_), dim3(256), 0, stream>>>(qm16, pj16, nd16);
    k_gemm<true><<<dim3(8, 64), dim3(256), 0, stream>>>(nd16, wf16, (void*)out);
}

// Round 2
// 403.306 us; speedup vs baseline: 1.0030x; 1.0030x over previous
//
#include <hip/hip_runtime.h>

#define B_ 4
#define W_ 2048
#define C_ 1024
#define NH 16
#define KH 64

typedef __attribute__((ext_vector_type(8))) short short8;
typedef __attribute__((ext_vector_type(4))) short s16x4;
typedef __attribute__((ext_vector_type(4))) float f32x4;

__device__ __forceinline__ short f2bf(float f) {
    unsigned u = __builtin_bit_cast(unsigned, f);
    u = (u + 0x7FFFu + ((u >> 16) & 1u)) >> 16;
    return (short)u;
}

// ---------------- metric[n] = P[n] @ P[n]^T ----------------
__global__ __launch_bounds__(256) void k_metric(const float* __restrict__ P, float* __restrict__ M) {
    int n = blockIdx.x;
    __shared__ float sP[KH * KH];
    __shared__ float sPt[KH * 65];
    const float* Pn = P + n * KH * KH;
    for (int i = threadIdx.x; i < KH * KH; i += 256) {
        float v = Pn[i];
        sP[i] = v;
        sPt[(i & 63) * 65 + (i >> 6)] = v;
    }
    __syncthreads();
    float* Mn = M + n * KH * KH;
    for (int e = threadIdx.x; e < KH * KH; e += 256) {
        int i = e >> 6, k = e & 63;
        float s = 0.f;
        #pragma unroll 8
        for (int j = 0; j < KH; ++j) s += sP[i * KH + j] * sPt[j * 65 + k];
        Mn[e] = s;
    }
}

// ---------------- Wq[n*64+jj][c] = 0.125 * sum_k M[n][k][jj] * Wp[n*64+k][c] ----------------
__global__ __launch_bounds__(256) void k_wq(const float* __restrict__ M, const float* __restrict__ Wp,
                                            short* __restrict__ Wq) {
    int n = blockIdx.y, cseg = blockIdx.x;
    __shared__ float sM[KH * KH];
    __shared__ float sW[KH * KH];
    for (int i = threadIdx.x; i < KH * KH; i += 256) {
        sM[i] = M[n * KH * KH + i];
        int r = i >> 6, c = i & 63;
        sW[i] = Wp[(n * KH + r) * C_ + cseg * KH + c];
    }
    __syncthreads();
    for (int e = threadIdx.x; e < KH * KH; e += 256) {
        int jj = e >> 6, c = e & 63;
        float s = 0.f;
        #pragma unroll 8
        for (int k = 0; k < KH; ++k) s += sM[k * KH + jj] * sW[k * KH + c];
        Wq[(n * KH + jj) * C_ + cseg * KH + c] = f2bf(s * 0.125f);   // fold 1/sqrt(K)
    }
}

// ---------------- Wf[o][n*64+k] = sum_j T[n][k][j] * Wm[o][n*64+j] ----------------
__global__ __launch_bounds__(256) void k_wf(const float* __restrict__ T, const float* __restrict__ Wm,
                                            short* __restrict__ Wf) {
    int n = blockIdx.y, oseg = blockIdx.x;
    __shared__ float sTt[KH * 65];
    __shared__ float sW[KH * KH];
    for (int i = threadIdx.x; i < KH * KH; i += 256) {
        sTt[(i & 63) * 65 + (i >> 6)] = T[n * KH * KH + i];
        int r = i >> 6, c = i & 63;
        sW[i] = Wm[(oseg * KH + r) * C_ + n * KH + c];
    }
    __syncthreads();
    for (int e = threadIdx.x; e < KH * KH; e += 256) {
        int r = e >> 6, k = e & 63;
        float s = 0.f;
        #pragma unroll 8
        for (int j = 0; j < KH; ++j) s += sTt[j * 65 + k] * sW[r * KH + j];
        Wf[(oseg * KH + r) * C_ + n * KH + k] = f2bf(s);
    }
}

// ---------------- fp32 -> bf16 convert ----------------
__global__ __launch_bounds__(256) void k_cvt(const float* __restrict__ src, short* __restrict__ dst, int n4) {
    int i = blockIdx.x * 256 + threadIdx.x;
    if (i < n4) {
        float4 v = ((const float4*)src)[i];
        short4 o;
        o.x = f2bf(v.x); o.y = f2bf(v.y); o.z = f2bf(v.z); o.w = f2bf(v.w);
        ((short4*)dst)[i] = o;
    }
}

// ---------------- per-(b,n) transpose: Ptg[(b*16+n)*64+k][w] = Pj[b][w][n*64+k] ----------------
__global__ __launch_bounds__(256) void k_tr(const short* __restrict__ src, short* __restrict__ dst) {
    int wt = blockIdx.x, bn = blockIdx.y;
    int b = bn >> 4, n = bn & 15;
    __shared__ short ld[64 * 72];
    int t = threadIdx.x;
    #pragma unroll
    for (int e = 0; e < 2; ++e) {
        int ch = e * 256 + t, row = ch >> 3, sub = ch & 7;
        *(short8*)&ld[row * 72 + sub * 8] =
            *(const short8*)&src[(b * W_ + wt * 64 + row) * C_ + n * KH + sub * 8];
    }
    __syncthreads();
    #pragma unroll
    for (int e = 0; e < 2; ++e) {
        int ch = e * 256 + t, krow = ch >> 3, sub = ch & 7;
        short8 v;
        #pragma unroll
        for (int j = 0; j < 8; ++j) v[j] = ld[(sub * 8 + j) * 72 + krow];
        *(short8*)&dst[(bn * KH + krow) * W_ + wt * 64 + sub * 8] = v;
    }
}

// ---------------- Out[M][1024] = A[M][1024] @ Bw[1024][1024]^T ----------------
template <bool OUT_FP32>
__global__ __launch_bounds__(256) void k_gemm(const short* __restrict__ A, const short* __restrict__ Bw,
                                              void* __restrict__ Out) {
    __shared__ short As[128 * 72];
    __shared__ short Bs[128 * 72];
    int bm = blockIdx.y, bn = blockIdx.x;
    int t = threadIdx.x;
    int wave = t >> 6, lane = t & 63;
    int q = lane >> 4, c = lane & 15;
    int wy = wave >> 1, wx = wave & 1;
    f32x4 acc[4][4] = {};
    for (int k0 = 0; k0 < C_; k0 += 64) {
        __syncthreads();
        #pragma unroll
        for (int e = 0; e < 4; ++e) {
            int ch = e * 256 + t;
            int row = ch >> 3, sub = ch & 7;
            *(short8*)&As[row * 72 + sub * 8] = *(const short8*)&A[(bm * 128 + row) * C_ + k0 + sub * 8];
            *(short8*)&Bs[row * 72 + sub * 8] = *(const short8*)&Bw[(bn * 128 + row) * C_ + k0 + sub * 8];
        }
        __syncthreads();
        #pragma unroll
        for (int kk = 0; kk < 64; kk += 32) {
            short8 af[4], bfr[4];
            #pragma unroll
            for (int i = 0; i < 4; ++i)
                af[i] = *(const short8*)&As[(wy * 64 + i * 16 + c) * 72 + kk + q * 8];
            #pragma unroll
            for (int j = 0; j < 4; ++j)
                bfr[j] = *(const short8*)&Bs[(wx * 64 + j * 16 + c) * 72 + kk + q * 8];
            #pragma unroll
            for (int i = 0; i < 4; ++i)
                #pragma unroll
                for (int j = 0; j < 4; ++j)
                    acc[i][j] = __builtin_amdgcn_mfma_f32_16x16x32_bf16(af[i], bfr[j], acc[i][j], 0, 0, 0);
        }
    }
    #pragma unroll
    for (int i = 0; i < 4; ++i)
        #pragma unroll
        for (int j = 0; j < 4; ++j)
            #pragma unroll
            for (int r = 0; r < 4; ++r) {
                int row = bm * 128 + wy * 64 + i * 16 + q * 4 + r;
                int col = bn * 128 + wx * 64 + j * 16 + c;
                if (OUT_FP32) ((float*)Out)[row * C_ + col] = acc[i][j][r];
                else ((short*)Out)[row * C_ + col] = f2bf(acc[i][j][r]);
            }
}

// ---------------- fused causal scores->nudged, all-vector-LDS version ----------------
// S^T = P_tile @ Qm_rows^T (Qm B-frags resident in registers); St[w][v] in LDS;
// O += St @ P via pre-transposed Pt tile. grid (32 wt, 16 n, 4 b) x 256.
__global__ __launch_bounds__(256) void k_flash(const short* __restrict__ Qm, const short* __restrict__ Pj,
                                               const short* __restrict__ Ptg, short* __restrict__ Nd) {
    int wt = 31 - blockIdx.x;          // heavy tiles first
    int n = blockIdx.y, b = blockIdx.z;
    int t = threadIdx.x, wave = t >> 6, lane = t & 63;
    int q = lane >> 4, c = lane & 15;
    __shared__ short Ps[64 * 72];      // P tile  [v][k]
    __shared__ short Pt[64 * 72];      // P^T tile [k][v]
    __shared__ short St[64 * 72];      // S^T as [w][v]
    int w0 = wt * 64;

    // resident Qm B-frags: lane holds Qm[w0+wtile*16+c][ch*32+q*8 ..+7]
    short8 bq[4][2];
    #pragma unroll
    for (int wtile = 0; wtile < 4; ++wtile)
        #pragma unroll
        for (int ch = 0; ch < 2; ++ch)
            bq[wtile][ch] = *(const short8*)&Qm[(b * W_ + w0 + wtile * 16 + c) * C_ + n * KH + ch * 32 + q * 8];

    f32x4 oc[4] = {};
    for (int vt = 0; vt <= wt; ++vt) {
        __syncthreads();               // prev iter's PV done with Pt/St
        #pragma unroll
        for (int e = 0; e < 2; ++e) {
            int ch = e * 256 + t, row = ch >> 3, sub = ch & 7;
            *(short8*)&Ps[row * 72 + sub * 8] =
                *(const short8*)&Pj[(b * W_ + vt * 64 + row) * C_ + n * KH + sub * 8];
            *(short8*)&Pt[row * 72 + sub * 8] =
                *(const short8*)&Ptg[((b * NH + n) * KH + row) * W_ + vt * 64 + sub * 8];
        }
        __syncthreads();
        // QK^T: wave computes S^T strip v_local in [wave*16, wave*16+16)
        short8 aP0 = *(const short8*)&Ps[(wave * 16 + c) * 72 + q * 8];
        short8 aP1 = *(const short8*)&Ps[(wave * 16 + c) * 72 + 32 + q * 8];
        f32x4 st[4] = {};
        #pragma unroll
        for (int wtile = 0; wtile < 4; ++wtile) {
            st[wtile] = __builtin_amdgcn_mfma_f32_16x16x32_bf16(aP0, bq[wtile][0], st[wtile], 0, 0, 0);
            st[wtile] = __builtin_amdgcn_mfma_f32_16x16x32_bf16(aP1, bq[wtile][1], st[wtile], 0, 0, 0);
        }
        // mask (diagonal tile only) + pack + vector store to St[w][v]
        bool diag = (vt == wt);
        int vbase = vt * 64 + wave * 16 + q * 4;
        #pragma unroll
        for (int wtile = 0; wtile < 4; ++wtile) {
            int wg = w0 + wtile * 16 + c;
            s16x4 pk;
            #pragma unroll
            for (int r = 0; r < 4; ++r) {
                float v = st[wtile][r];
                if (diag && (vbase + r > wg)) v = 0.f;
                pk[r] = f2bf(v);
            }
            *(s16x4*)&St[(wtile * 16 + c) * 72 + wave * 16 + q * 4] = pk;
        }
        __syncthreads();
        // PV: O rows w_local in [wave*16, wave*16+16)
        short8 as0 = *(const short8*)&St[(wave * 16 + c) * 72 + q * 8];
        short8 as1 = *(const short8*)&St[(wave * 16 + c) * 72 + 32 + q * 8];
        #pragma unroll
        for (int ct2 = 0; ct2 < 4; ++ct2) {
            short8 bp0 = *(const short8*)&Pt[(ct2 * 16 + c) * 72 + q * 8];
            short8 bp1 = *(const short8*)&Pt[(ct2 * 16 + c) * 72 + 32 + q * 8];
            oc[ct2] = __builtin_amdgcn_mfma_f32_16x16x32_bf16(as0, bp0, oc[ct2], 0, 0, 0);
            oc[ct2] = __builtin_amdgcn_mfma_f32_16x16x32_bf16(as1, bp1, oc[ct2], 0, 0, 0);
        }
    }
    #pragma unroll
    for (int ct2 = 0; ct2 < 4; ++ct2)
        #pragma unroll
        for (int r = 0; r < 4; ++r)
            Nd[(b * W_ + w0 + wave * 16 + q * 4 + r) * C_ + n * KH + ct2 * 16 + c] = f2bf(oc[ct2][r]);
}

extern "C" void kernel_launch(void* const* d_in, const int* in_sizes, int n_in,
                              void* d_out, int out_size, void* d_ws, size_t ws_size,
                              hipStream_t stream) {
    const float* x  = (const float*)d_in[0];
    const float* Wp = (const float*)d_in[1];
    const float* Pm = (const float*)d_in[2];
    const float* Tr = (const float*)d_in[3];
    const float* Wm = (const float*)d_in[4];
    float* out = (float*)d_out;
    char* ws = (char*)d_ws;

    const size_t MB = 1024 * 1024;
    float* metric = (float*)ws;                       // 256 KB
    short* wq16 = (short*)(ws + 256 * 1024);          // 2 MB
    short* wf16 = (short*)(ws + 256 * 1024 + 2 * MB); // 2 MB
    short* wp16 = (short*)(ws + 256 * 1024 + 4 * MB); // 2 MB
    short* x16  = (short*)(ws + 256 * 1024 + 6 * MB); // 16 MB
    short* pj16 = x16 + 8 * MB;                       // 16 MB
    short* qm16 = pj16 + 8 * MB;                      // 16 MB
    short* ptg  = qm16 + 8 * MB;                      // 16 MB
    short* nd16 = x16;                                // alias: x16 dead after GEMMs

    k_metric<<<dim3(NH), dim3(256), 0, stream>>>(Pm, metric);
    k_wq<<<dim3(16, NH), dim3(256), 0, stream>>>(metric, Wp, wq16);
    k_wf<<<dim3(16, NH), dim3(256), 0, stream>>>(Tr, Wm, wf16);
    k_cvt<<<dim3(8192), dim3(256), 0, stream>>>(x, x16, (B_ * W_ * C_) / 4);
    k_cvt<<<dim3(1024), dim3(256), 0, stream>>>(Wp, wp16, (C_ * C_) / 4);

    k_gemm<false><<<dim3(8, 64), dim3(256), 0, stream>>>(x16, wp16, (void*)pj16);
    k_gemm<false><<<dim3(8, 64), dim3(256), 0, stream>>>(x16, wq16, (void*)qm16);
    k_tr<<<dim3(32, 64), dim3(256), 0, stream>>>(pj16, ptg);
    k_flash<<<dim3(32, NH, B_), dim3(256), 0, stream>>>(qm16, pj16, ptg, nd16);
    k_gemm<true><<<dim3(8, 64), dim3(256), 0, stream>>>(nd16, wf16, (void*)out);
}

// Round 3
// 321.767 us; speedup vs baseline: 1.2572x; 1.2534x over previous
//
#include <hip/hip_runtime.h>

#define B_ 4
#define W_ 2048
#define C_ 1024
#define NH 16
#define KH 64

typedef __attribute__((ext_vector_type(8))) short short8;
typedef __attribute__((ext_vector_type(4))) short s16x4;
typedef __attribute__((ext_vector_type(4))) float f32x4;

__device__ __forceinline__ short f2bf(float f) {
    unsigned u = __builtin_bit_cast(unsigned, f);
    u = (u + 0x7FFFu + ((u >> 16) & 1u)) >> 16;
    return (short)u;
}

// ---------------- metric[n] = P[n] @ P[n]^T ----------------
__global__ __launch_bounds__(256) void k_metric(const float* __restrict__ P, float* __restrict__ M) {
    int n = blockIdx.x;
    __shared__ float sP[KH * KH];
    __shared__ float sPt[KH * 65];
    const float* Pn = P + n * KH * KH;
    for (int i = threadIdx.x; i < KH * KH; i += 256) {
        float v = Pn[i];
        sP[i] = v;
        sPt[(i & 63) * 65 + (i >> 6)] = v;
    }
    __syncthreads();
    float* Mn = M + n * KH * KH;
    for (int e = threadIdx.x; e < KH * KH; e += 256) {
        int i = e >> 6, k = e & 63;
        float s = 0.f;
        #pragma unroll 8
        for (int j = 0; j < KH; ++j) s += sP[i * KH + j] * sPt[j * 65 + k];
        Mn[e] = s;
    }
}

// ---------------- Wq[n*64+jj][c] = 0.125 * sum_k M[n][k][jj] * Wp[n*64+k][c] ----------------
__global__ __launch_bounds__(256) void k_wq(const float* __restrict__ M, const float* __restrict__ Wp,
                                            short* __restrict__ Wq) {
    int n = blockIdx.y, cseg = blockIdx.x;
    __shared__ float sM[KH * KH];
    __shared__ float sW[KH * KH];
    for (int i = threadIdx.x; i < KH * KH; i += 256) {
        sM[i] = M[n * KH * KH + i];
        int r = i >> 6, c = i & 63;
        sW[i] = Wp[(n * KH + r) * C_ + cseg * KH + c];
    }
    __syncthreads();
    for (int e = threadIdx.x; e < KH * KH; e += 256) {
        int jj = e >> 6, c = e & 63;
        float s = 0.f;
        #pragma unroll 8
        for (int k = 0; k < KH; ++k) s += sM[k * KH + jj] * sW[k * KH + c];
        Wq[(n * KH + jj) * C_ + cseg * KH + c] = f2bf(s * 0.125f);   // fold 1/sqrt(K)
    }
}

// ---------------- Wf[o][n*64+k] = sum_j T[n][k][j] * Wm[o][n*64+j] ----------------
__global__ __launch_bounds__(256) void k_wf(const float* __restrict__ T, const float* __restrict__ Wm,
                                            short* __restrict__ Wf) {
    int n = blockIdx.y, oseg = blockIdx.x;
    __shared__ float sTt[KH * 65];
    __shared__ float sW[KH * KH];
    for (int i = threadIdx.x; i < KH * KH; i += 256) {
        sTt[(i & 63) * 65 + (i >> 6)] = T[n * KH * KH + i];
        int r = i >> 6, c = i & 63;
        sW[i] = Wm[(oseg * KH + r) * C_ + n * KH + c];
    }
    __syncthreads();
    for (int e = threadIdx.x; e < KH * KH; e += 256) {
        int r = e >> 6, k = e & 63;
        float s = 0.f;
        #pragma unroll 8
        for (int j = 0; j < KH; ++j) s += sTt[j * 65 + k] * sW[r * KH + j];
        Wf[(oseg * KH + r) * C_ + n * KH + k] = f2bf(s);
    }
}

// ---------------- fp32 -> bf16 convert ----------------
__global__ __launch_bounds__(256) void k_cvt(const float* __restrict__ src, short* __restrict__ dst, int n4) {
    int i = blockIdx.x * 256 + threadIdx.x;
    if (i < n4) {
        float4 v = ((const float4*)src)[i];
        short4 o;
        o.x = f2bf(v.x); o.y = f2bf(v.y); o.z = f2bf(v.z); o.w = f2bf(v.w);
        ((short4*)dst)[i] = o;
    }
}

// ---------------- per-(b,n) transpose: Ptg[(b*16+n)*64+k][w] = Pj[b][w][n*64+k] ----------------
__global__ __launch_bounds__(256) void k_tr(const short* __restrict__ src, short* __restrict__ dst) {
    int wt = blockIdx.x, bn = blockIdx.y;
    int b = bn >> 4, n = bn & 15;
    __shared__ short ld[64 * 72];
    int t = threadIdx.x;
    #pragma unroll
    for (int e = 0; e < 2; ++e) {
        int ch = e * 256 + t, row = ch >> 3, sub = ch & 7;
        *(short8*)&ld[row * 72 + sub * 8] =
            *(const short8*)&src[(b * W_ + wt * 64 + row) * C_ + n * KH + sub * 8];
    }
    __syncthreads();
    #pragma unroll
    for (int e = 0; e < 2; ++e) {
        int ch = e * 256 + t, krow = ch >> 3, sub = ch & 7;
        short8 v;
        #pragma unroll
        for (int j = 0; j < 8; ++j) v[j] = ld[(sub * 8 + j) * 72 + krow];
        *(short8*)&dst[(bn * KH + krow) * W_ + wt * 64 + sub * 8] = v;
    }
}

// ---------------- Out[M][1024] = A[M][1024] @ Bw[1024][1024]^T ----------------
template <bool OUT_FP32>
__global__ __launch_bounds__(256) void k_gemm(const short* __restrict__ A, const short* __restrict__ Bw,
                                              void* __restrict__ Out) {
    __shared__ short As[128 * 72];
    __shared__ short Bs[128 * 72];
    int bm = blockIdx.y, bn = blockIdx.x;
    int t = threadIdx.x;
    int wave = t >> 6, lane = t & 63;
    int q = lane >> 4, c = lane & 15;
    int wy = wave >> 1, wx = wave & 1;
    f32x4 acc[4][4] = {};
    for (int k0 = 0; k0 < C_; k0 += 64) {
        __syncthreads();
        #pragma unroll
        for (int e = 0; e < 4; ++e) {
            int ch = e * 256 + t;
            int row = ch >> 3, sub = ch & 7;
            *(short8*)&As[row * 72 + sub * 8] = *(const short8*)&A[(bm * 128 + row) * C_ + k0 + sub * 8];
            *(short8*)&Bs[row * 72 + sub * 8] = *(const short8*)&Bw[(bn * 128 + row) * C_ + k0 + sub * 8];
        }
        __syncthreads();
        #pragma unroll
        for (int kk = 0; kk < 64; kk += 32) {
            short8 af[4], bfr[4];
            #pragma unroll
            for (int i = 0; i < 4; ++i)
                af[i] = *(const short8*)&As[(wy * 64 + i * 16 + c) * 72 + kk + q * 8];
            #pragma unroll
            for (int j = 0; j < 4; ++j)
                bfr[j] = *(const short8*)&Bs[(wx * 64 + j * 16 + c) * 72 + kk + q * 8];
            #pragma unroll
            for (int i = 0; i < 4; ++i)
                #pragma unroll
                for (int j = 0; j < 4; ++j)
                    acc[i][j] = __builtin_amdgcn_mfma_f32_16x16x32_bf16(af[i], bfr[j], acc[i][j], 0, 0, 0);
        }
    }
    #pragma unroll
    for (int i = 0; i < 4; ++i)
        #pragma unroll
        for (int j = 0; j < 4; ++j)
            #pragma unroll
            for (int r = 0; r < 4; ++r) {
                int row = bm * 128 + wy * 64 + i * 16 + q * 4 + r;
                int col = bn * 128 + wx * 64 + j * 16 + c;
                if (OUT_FP32) ((float*)Out)[row * C_ + col] = acc[i][j][r];
                else ((short*)Out)[row * C_ + col] = f2bf(acc[i][j][r]);
            }
}

// ---------------- fused causal scores->nudged, BM=128 + register-prefetch pipeline ----------------
// grid (16 wt, 16 n, 4 b) x 512 (8 waves). v-tile = 64. Qm B-frags resident in regs.
// QK: wave = (wh: w-half 0..1, wv: v-strip 0..3) computes S^T; St[w][v] in LDS.
// PV: wave owns 16 w-rows; B-frags from pre-transposed Pt tile.
__global__ __launch_bounds__(512, 4) void k_flash(const short* __restrict__ Qm, const short* __restrict__ Pj,
                                                  const short* __restrict__ Ptg, short* __restrict__ Nd) {
    int wt = 15 - (int)blockIdx.x;     // heavy tiles first
    int n = blockIdx.y, b = blockIdx.z;
    int t = threadIdx.x, wave = t >> 6, lane = t & 63;
    int q = lane >> 4, c = lane & 15;
    int wh = wave >> 2;                // w-half for QK phase
    int wv = wave & 3;                 // v-strip for QK phase
    __shared__ short Ps[64 * 72];      // P tile   [v][k]
    __shared__ short Pt[64 * 72];      // P^T tile [k][v]
    __shared__ short St[128 * 72];     // S as [w][v]
    int w0 = wt * 128;

    // resident Qm B-frags for this wave's w-half
    short8 bq[4][2];
    #pragma unroll
    for (int wtile = 0; wtile < 4; ++wtile)
        #pragma unroll
        for (int ch = 0; ch < 2; ++ch)
            bq[wtile][ch] = *(const short8*)&Qm[(b * W_ + w0 + wh * 64 + wtile * 16 + c) * C_
                                                + n * KH + ch * 32 + q * 8];

    // staging addresses: 512 threads cover 64 rows x 8 sub-chunks of 8 bf16
    int srow = t >> 3, ssub = t & 7;
    const short* psrc = &Pj[(b * W_ + srow) * C_ + n * KH + ssub * 8];
    const short* tsrc = &Ptg[((b * NH + n) * KH + srow) * W_ + ssub * 8];
    short* pdst = &Ps[srow * 72 + ssub * 8];
    short* tdst = &Pt[srow * 72 + ssub * 8];

    f32x4 oc[4] = {};
    int vmax = 2 * wt + 1;
    short8 pfA = *(const short8*)psrc;          // prefetch v-tile 0
    short8 pfB = *(const short8*)tsrc;

    for (int vt = 0; vt <= vmax; ++vt) {
        __syncthreads();                         // prev iter's PV done with Pt/St
        *(short8*)pdst = pfA;
        *(short8*)tdst = pfB;
        if (vt < vmax) {                         // prefetch next tile; vmcnt waits at next write
            pfA = *(const short8*)(psrc + (size_t)(vt + 1) * 64 * C_);
            pfB = *(const short8*)(tsrc + (vt + 1) * 64);
        }
        __syncthreads();
        // QK: S^T strip (v = wv*16.., w = wh*64..)
        short8 aP0 = *(const short8*)&Ps[(wv * 16 + c) * 72 + q * 8];
        short8 aP1 = *(const short8*)&Ps[(wv * 16 + c) * 72 + 32 + q * 8];
        f32x4 st[4] = {};
        #pragma unroll
        for (int wtile = 0; wtile < 4; ++wtile) {
            st[wtile] = __builtin_amdgcn_mfma_f32_16x16x32_bf16(aP0, bq[wtile][0], st[wtile], 0, 0, 0);
            st[wtile] = __builtin_amdgcn_mfma_f32_16x16x32_bf16(aP1, bq[wtile][1], st[wtile], 0, 0, 0);
        }
        bool diag = (vt >= 2 * wt);              // only last two v-tiles touch the diagonal
        int vbase = vt * 64 + wv * 16 + q * 4;
        #pragma unroll
        for (int wtile = 0; wtile < 4; ++wtile) {
            int wg = w0 + wh * 64 + wtile * 16 + c;
            s16x4 pk;
            #pragma unroll
            for (int r = 0; r < 4; ++r) {
                float v = st[wtile][r];
                if (diag && (vbase + r > wg)) v = 0.f;
                pk[r] = f2bf(v);
            }
            *(s16x4*)&St[(wh * 64 + wtile * 16 + c) * 72 + wv * 16 + q * 4] = pk;
        }
        __syncthreads();
        // PV: wave owns w-rows [wave*16, wave*16+16)
        short8 as0 = *(const short8*)&St[(wave * 16 + c) * 72 + q * 8];
        short8 as1 = *(const short8*)&St[(wave * 16 + c) * 72 + 32 + q * 8];
        #pragma unroll
        for (int ct2 = 0; ct2 < 4; ++ct2) {
            short8 bp0 = *(const short8*)&Pt[(ct2 * 16 + c) * 72 + q * 8];
            short8 bp1 = *(const short8*)&Pt[(ct2 * 16 + c) * 72 + 32 + q * 8];
            oc[ct2] = __builtin_amdgcn_mfma_f32_16x16x32_bf16(as0, bp0, oc[ct2], 0, 0, 0);
            oc[ct2] = __builtin_amdgcn_mfma_f32_16x16x32_bf16(as1, bp1, oc[ct2], 0, 0, 0);
        }
    }
    #pragma unroll
    for (int ct2 = 0; ct2 < 4; ++ct2)
        #pragma unroll
        for (int r = 0; r < 4; ++r)
            Nd[(b * W_ + w0 + wave * 16 + q * 4 + r) * C_ + n * KH + ct2 * 16 + c] = f2bf(oc[ct2][r]);
}

extern "C" void kernel_launch(void* const* d_in, const int* in_sizes, int n_in,
                              void* d_out, int out_size, void* d_ws, size_t ws_size,
                              hipStream_t stream) {
    const float* x  = (const float*)d_in[0];
    const float* Wp = (const float*)d_in[1];
    const float* Pm = (const float*)d_in[2];
    const float* Tr = (const float*)d_in[3];
    const float* Wm = (const float*)d_in[4];
    float* out = (float*)d_out;
    char* ws = (char*)d_ws;

    const size_t MB = 1024 * 1024;
    float* metric = (float*)ws;                       // 256 KB
    short* wq16 = (short*)(ws + 256 * 1024);          // 2 MB
    short* wf16 = (short*)(ws + 256 * 1024 + 2 * MB); // 2 MB
    short* wp16 = (short*)(ws + 256 * 1024 + 4 * MB); // 2 MB
    short* x16  = (short*)(ws + 256 * 1024 + 6 * MB); // 16 MB
    short* pj16 = x16 + 8 * MB;                       // 16 MB
    short* qm16 = pj16 + 8 * MB;                      // 16 MB
    short* ptg  = qm16 + 8 * MB;                      // 16 MB
    short* nd16 = x16;                                // alias: x16 dead after GEMMs

    k_metric<<<dim3(NH), dim3(256), 0, stream>>>(Pm, metric);
    k_wq<<<dim3(16, NH), dim3(256), 0, stream>>>(metric, Wp, wq16);
    k_wf<<<dim3(16, NH), dim3(256), 0, stream>>>(Tr, Wm, wf16);
    k_cvt<<<dim3(8192), dim3(256), 0, stream>>>(x, x16, (B_ * W_ * C_) / 4);
    k_cvt<<<dim3(1024), dim3(256), 0, stream>>>(Wp, wp16, (C_ * C_) / 4);

    k_gemm<false><<<dim3(8, 64), dim3(256), 0, stream>>>(x16, wp16, (void*)pj16);
    k_gemm<false><<<dim3(8, 64), dim3(256), 0, stream>>>(x16, wq16, (void*)qm16);
    k_tr<<<dim3(32, 64), dim3(256), 0, stream>>>(pj16, ptg);
    k_flash<<<dim3(16, NH, B_), dim3(512), 0, stream>>>(qm16, pj16, ptg, nd16);
    k_gemm<true><<<dim3(8, 64), dim3(256), 0, stream>>>(nd16, wf16, (void*)out);
}